// Round 7
// baseline (253.312 us; speedup 1.0000x reference)
//
#include <hip/hip_runtime.h>

// Problem constants
#define D_    2048
#define OUT_  2048
#define E_    8
#define R_    16
#define KX    2176          // D_ + E_*R_  (K-extended GEMM depth)
#define M_    16384         // B*S tokens
#define SCALING_F 2.0f      // ALPHA / R = 32/16

typedef unsigned short ushort_t;
typedef unsigned short ushort8 __attribute__((ext_vector_type(8)));
typedef __bf16 bf16x8 __attribute__((ext_vector_type(8)));
typedef float f32x4 __attribute__((ext_vector_type(4)));

__device__ __forceinline__ ushort_t f2bf(float f) {
  unsigned u = __float_as_uint(f);
  u += 0x7FFFu + ((u >> 16) & 1u);   // round-to-nearest-even
  return (ushort_t)(u >> 16);
}

#define GLOAD16(gp, lp)                                                        \
  __builtin_amdgcn_global_load_lds(                                            \
      (const __attribute__((address_space(1))) void*)(gp),                     \
      (__attribute__((address_space(3))) void*)(lp), 16, 0, 0)

// -------- W_ext + A_ext prep (fused): wext[OUT_][KX], aext[128][D_] bf16 ----
__global__ __launch_bounds__(256) void wprep_all_kernel(
    const float* __restrict__ W, const float* __restrict__ Bw,
    const float* __restrict__ A,
    ushort_t* __restrict__ wext, ushort_t* __restrict__ aext)
{
  const int bid = blockIdx.x;
  const int t = threadIdx.x;
  if (bid < OUT_) {
    const int o = bid;
    const float* wr = W + (size_t)o * D_ + t * 8;
    float4 v0 = *(const float4*)wr;
    float4 v1 = *(const float4*)(wr + 4);
    ushort8 wb;
    wb[0] = f2bf(v0.x); wb[1] = f2bf(v0.y); wb[2] = f2bf(v0.z); wb[3] = f2bf(v0.w);
    wb[4] = f2bf(v1.x); wb[5] = f2bf(v1.y); wb[6] = f2bf(v1.z); wb[7] = f2bf(v1.w);
    *(ushort8*)(wext + (size_t)o * KX + t * 8) = wb;
    if (t < E_ * R_) {
      const int e = t >> 4, r = t & 15;
      wext[(size_t)o * KX + D_ + t] = f2bf(Bw[((size_t)e * OUT_ + o) * R_ + r]);
    }
  } else {
    const size_t i = ((size_t)(bid - OUT_) * 256 + t) * 8;
    float4 v0 = *(const float4*)(A + i);
    float4 v1 = *(const float4*)(A + i + 4);
    ushort8 b;
    b[0] = f2bf(v0.x); b[1] = f2bf(v0.y); b[2] = f2bf(v0.z); b[3] = f2bf(v0.w);
    b[4] = f2bf(v1.x); b[5] = f2bf(v1.y); b[6] = f2bf(v1.z); b[7] = f2bf(v1.w);
    *(ushort8*)(aext + i) = b;
  }
}

// ---------------- router: logits + argmax only (no xext writes) -------------
// 4 tokens/wave; fp32 xor1/2/4 reduce then fp64 xor8/16/32 (argmax precision).
__global__ __launch_bounds__(256) void router_kernel(
    const float* __restrict__ x, const float* __restrict__ rW,
    int* __restrict__ eidx)
{
  const int t = threadIdx.x, lane = t & 63, wid = t >> 6;
  const int m0 = (blockIdx.x * 4 + wid) * 4;   // first of 4 tokens for this wave

  float acc[4][E_];
  #pragma unroll
  for (int k = 0; k < 4; ++k)
    #pragma unroll
    for (int e = 0; e < E_; ++e) acc[k][e] = 0.f;

  #pragma unroll
  for (int j = 0; j < 8; ++j) {
    const int col = j * 256 + lane * 4;
    float4 w[E_];
    #pragma unroll
    for (int e = 0; e < E_; ++e)
      w[e] = *(const float4*)(rW + (size_t)e * D_ + col);
    #pragma unroll
    for (int k = 0; k < 4; ++k) {
      float4 xv = *(const float4*)(x + (size_t)(m0 + k) * D_ + col);
      #pragma unroll
      for (int e = 0; e < E_; ++e)
        acc[k][e] += xv.x * w[e].x + xv.y * w[e].y + xv.z * w[e].z + xv.w * w[e].w;
    }
  }

  #pragma unroll
  for (int k = 0; k < 4; ++k) {
    float r[E_];
    #pragma unroll
    for (int e = 0; e < E_; ++e) r[e] = acc[k][e];
    #pragma unroll
    for (int off = 1; off <= 4; off <<= 1)
      #pragma unroll
      for (int e = 0; e < E_; ++e) r[e] += __shfl_xor(r[e], off, 64);
    double s[E_];
    #pragma unroll
    for (int e = 0; e < E_; ++e) s[e] = (double)r[e];
    #pragma unroll
    for (int off = 8; off <= 32; off <<= 1)
      #pragma unroll
      for (int e = 0; e < E_; ++e) s[e] += __shfl_xor(s[e], off, 64);
    int bi = 0; double best = s[0];
    #pragma unroll
    for (int e = 1; e < E_; ++e)
      if (s[e] > best) { best = s[e]; bi = e; }   // first-max tie-break
    if (lane == 0) eidx[m0 + k] = bi;
  }
}

// ------- h GEMM + x convert (fused): reads x fp32, writes FULL xext row -----
// Counted-wait pipeline (no __syncthreads vmcnt(0) drain):
//   per tile T: stageA(T+1) DMA [4 vm] ; xload(T+2) -> regs [2 vm] ;
//   ds_read + MFMA on buf[T&1] ; putX(T+1) (ds_write buf^1 + gstore [1 vm]) ;
//   s_waitcnt vmcnt(3) lgkmcnt(0)  <- drains stageA, keeps xload+gstore ;
//   s_barrier.
// Race-safety: all LDS writes (stageA DMA, putX ds_write) target buf[(T+1)&1]
// == never the buffer read this tile; DMA drained by counted vmcnt pre-barrier,
// ds_write drained by lgkmcnt(0) pre-barrier.
#define HG_NKT (D_ / 64)     // 32 K-tiles

__global__ __launch_bounds__(256) void hgemm_kernel(
    const float* __restrict__ x,       // [M_][D_] fp32
    const ushort_t* __restrict__ Ae,   // [128][D_] bf16
    const int* __restrict__ eidx,
    ushort_t* __restrict__ xext)       // writes all KX cols
{
  __shared__ __attribute__((aligned(16))) char lds[40960];  // 2 x (4KB X + 16KB A)

  const int t = threadIdx.x;
  const int lane = t & 63, w = t >> 6;
  const int wr = w >> 1, wc = w & 1;          // wave tile 16 rows x 64 cols
  const int lr = lane & 15, lg = lane >> 4;
  const int koff = (lr & 7) << 4;

  const int bm = blockIdx.x;                   // 512 blocks x 32 rows
  const size_t row0 = (size_t)bm * 32;

  const int sg_row = t >> 3;                   // 0..31
  const int sg_c = t & 7;                      // col chunk (8 bf16)
  const int sg_slotx = sg_c ^ (sg_row & 7);    // pre-swizzled slot

  // stage Ae tile TT into buffer (TT&1): 128 rows x 64 cols bf16
  auto stageA = [&](int TT) {
    char* dst = lds + (TT & 1) * 20480 + 4096;
    #pragma unroll
    for (int g = 0; g < 4; ++g) {
      const int r = g * 32 + sg_row;
      GLOAD16(Ae + (size_t)r * D_ + TT * 64 + sg_slotx * 8,
              dst + g * 4096 + t * 16);
    }
  };
  // convert 8 x-floats and write LDS (swizzled) + global xext core
  auto putX = [&](int TT, const float4& a, const float4& b) {
    ushort8 xb;
    xb[0] = f2bf(a.x); xb[1] = f2bf(a.y); xb[2] = f2bf(a.z); xb[3] = f2bf(a.w);
    xb[4] = f2bf(b.x); xb[5] = f2bf(b.y); xb[6] = f2bf(b.z); xb[7] = f2bf(b.w);
    char* Xb = lds + (TT & 1) * 20480;
    *(ushort8*)(Xb + sg_row * 128 + sg_slotx * 16) = xb;
    *(ushort8*)(xext + (row0 + sg_row) * KX + TT * 64 + sg_c * 8) = xb;
  };

  f32x4 acc[4] = {};
  const float* xp = x + (row0 + sg_row) * D_ + sg_c * 8;

  // prologue: x(0), stageA(0), x(1); produce tile 0; counted drain.
  float4 xb0, xb1;
  {
    float4 xa0 = *(const float4*)xp;
    float4 xa1 = *(const float4*)(xp + 4);
    stageA(0);
    xb0 = *(const float4*)(xp + 64);
    xb1 = *(const float4*)(xp + 68);
    putX(0, xa0, xa1);
    // drain stageA(0) [4 oldest after xa consumed]; keep x(1) 2 + gstore 1
    asm volatile("s_waitcnt vmcnt(3) lgkmcnt(0)" ::: "memory");
    __builtin_amdgcn_s_barrier();
  }

  for (int T = 0; T < HG_NKT; ++T) {
    if (T + 1 < HG_NKT) stageA(T + 1);
    float4 xc0, xc1;
    if (T + 2 < HG_NKT) {
      xc0 = *(const float4*)(xp + (T + 2) * 64);
      xc1 = *(const float4*)(xp + (T + 2) * 64 + 4);
    }
    char* Xb = lds + (T & 1) * 20480;
    char* Ab = Xb + 4096;
    bf16x8 af[2], bfr[4][2];
    #pragma unroll
    for (int kk = 0; kk < 2; ++kk)
      af[kk] = *(const bf16x8*)(Xb + (wr * 16 + lr) * 128 + ((kk * 64 + lg * 16) ^ koff));
    #pragma unroll
    for (int nj = 0; nj < 4; ++nj) {
      const int R = wc * 64 + nj * 16 + lr;
      #pragma unroll
      for (int kk = 0; kk < 2; ++kk)
        bfr[nj][kk] = *(const bf16x8*)(Ab + R * 128 + ((kk * 64 + lg * 16) ^ koff));
    }
    #pragma unroll
    for (int nj = 0; nj < 4; ++nj)
      #pragma unroll
      for (int kk = 0; kk < 2; ++kk)
        acc[nj] = __builtin_amdgcn_mfma_f32_16x16x32_bf16(af[kk], bfr[nj][kk], acc[nj], 0, 0, 0);
    if (T + 1 < HG_NKT) putX(T + 1, xb0, xb1);
    if (T < HG_NKT - 1) {
      // steady: drain stageA(T+1); keep xload(T+2) 2 + gstore 1.
      // T==HG_NKT-2: no xload issued -> drain to gstore only.
      if (T == HG_NKT - 2) asm volatile("s_waitcnt vmcnt(1) lgkmcnt(0)" ::: "memory");
      else                 asm volatile("s_waitcnt vmcnt(3) lgkmcnt(0)" ::: "memory");
      __builtin_amdgcn_s_barrier();
    }
    xb0 = xc0; xb1 = xc1;
  }

  // masked epilogue: xext[row][D_+col] = (eidx[row]==col>>4) ? bf16(2*h) : 0
  int er[4];
  #pragma unroll
  for (int rr = 0; rr < 4; ++rr)
    er[rr] = eidx[row0 + wr * 16 + lg * 4 + rr];
  #pragma unroll
  for (int nj = 0; nj < 4; ++nj) {
    const int col = wc * 64 + nj * 16 + lr;
    const int ecol = wc * 4 + nj;              // col>>4, wave-uniform per nj
    #pragma unroll
    for (int rr = 0; rr < 4; ++rr) {
      const size_t row = row0 + wr * 16 + lg * 4 + rr;
      ushort_t v = (er[rr] == ecol) ? f2bf(acc[nj][rr] * SCALING_F) : (ushort_t)0;
      xext[row * KX + D_ + col] = v;
    }
  }
}

// ---------------- GEMM: 256x256 tile, 8-phase schedule (m201 template) ------
// BM=BN=256, BK=64, 8 waves (2Mx4N), 512 thr, 128 KiB LDS double-buffer.
// T2 st-swizzle (slot^row&7 both sides), counted vmcnt(4)/K-tile, setprio.
//
// RACE-SAFE stage schedule (round-6 invariants, deeper A window):
//   A-region of buffer T&1 is ds_read in EVERY phase of tile T -> A halves
//   staged 1-ahead only (buffer (T+1)&1, never the read buffer) — BOTH at q0
//   so the forced q3 drain gives them ~3 phases of flight (round 6 staged A1
//   at q1 -> ~2 phases -> stall).
//   B-region of buffer T&1 is ds_read ONLY at q0 (cached in bq regs), drained
//   by q0's lgkmcnt(0) -> B halves of tile T+2 safe to stage at q>=2.
//   Per tile T: q0 -> A0(T+1)+A1(T+1); q2 -> B0(T+2); q3 -> B1(T+2).
//   q3 issue order ledger: B(T+1)[T-1 q2/q3], A(T+1)[q0], B(T+2)[q2/q3] = 12
//   outstanding -> vmcnt(4) drains B(T+1)+A(T+1), keeps B(T+2) in flight.
#define NKT (KX / 64)        // 34 K-tiles
#define NSTG (NKT * 4)       // 136 half-tile stages

__global__ __launch_bounds__(512, 2) void gemm_kernel(
    const ushort_t* __restrict__ Ag,   // [M_][KX] bf16
    const ushort_t* __restrict__ Bg,   // [OUT_][KX] bf16
    const float* __restrict__ bias,
    float* __restrict__ C)
{
  __shared__ __attribute__((aligned(16))) char lds[131072];

  const int t = threadIdx.x;
  const int lane = t & 63, w = t >> 6;
  const int wm = w >> 2, wn = w & 3;          // 2x4 wave grid; wave tile 128x64
  const int lr = lane & 15, lg = lane >> 4;
  const int koff = (lr & 7) << 4;             // read-side swizzle XOR (bytes)

  // XCD-bijective blockIdx swizzle (512 % 8 == 0)
  const int swz = (blockIdx.x & 7) * 64 + (blockIdx.x >> 3);
  const int bm = swz >> 3, bn = swz & 7;

  // staging constants: thread t covers row (g*64 + t>>3), slot (t&7)
  const int sg_row = t >> 3;
  const int sg_slotx = (t & 7) ^ ((t >> 3) & 7);   // pre-swizzled source slot
  const size_t aRow0 = (size_t)bm * 256;
  const size_t bRow0 = (size_t)bn * 256;

  // stage half-tile s: tile TT=s>>2, j=s&3 (0,1 = A halves; 2,3 = B halves)
  auto stage = [&](int s) {
    if (s >= NSTG) return;
    const int TT = s >> 2, j = s & 3;
    const int isB = j >> 1, half = j & 1;
    const ushort_t* src = isB ? Bg : Ag;
    const size_t gr0 = (isB ? bRow0 : aRow0) + half * 128;
    char* dst = lds + (TT & 1) * 65536 + isB * 32768 + half * 16384;
    #pragma unroll
    for (int g = 0; g < 2; ++g) {
      const int r = g * 64 + sg_row;
      GLOAD16(src + (gr0 + r) * KX + TT * 64 + sg_slotx * 8,
              dst + g * 8192 + t * 16);
    }
  };

  f32x4 acc[8][4] = {};
  bf16x8 bq[4][2];

  // prologue: tile0 {A0,A1,B0,B1} + tile1 {B0,B1}; wait tile0 landed,
  // leaving tile1's B (4 loads) in flight. (Tile1's A staged at T=0 q0.)
  stage(0); stage(1); stage(2); stage(3);
  stage(6); stage(7);
  asm volatile("s_waitcnt vmcnt(4)" ::: "memory");
  __builtin_amdgcn_s_barrier();

  #pragma unroll 2
  for (int T = 0; T < NKT; ++T) {
    char* Ab = lds + (T & 1) * 65536;
    char* Bb = Ab + 32768;
    #pragma unroll
    for (int q = 0; q < 4; ++q) {
      // --- ds-load register subtile ---
      bf16x8 aq[2][2];
      if (q == 0) {
        #pragma unroll
        for (int nj = 0; nj < 4; ++nj) {
          const int R = wn * 64 + nj * 16 + lr;
          #pragma unroll
          for (int kk = 0; kk < 2; ++kk)
            bq[nj][kk] = *(const bf16x8*)(Bb + R * 128 + ((kk * 64 + lg * 16) ^ koff));
        }
      }
      #pragma unroll
      for (int i = 0; i < 2; ++i) {
        const int R = wm * 128 + (q * 2 + i) * 16 + lr;
        #pragma unroll
        for (int kk = 0; kk < 2; ++kk)
          aq[i][kk] = *(const bf16x8*)(Ab + R * 128 + ((kk * 64 + lg * 16) ^ koff));
      }
      // --- stage schedule: q0 -> both A halves of T+1; q2/q3 -> B of T+2 ---
      if (q == 0)      { stage(4 * (T + 1));     stage(4 * (T + 1) + 1); }
      else if (q == 2)   stage(4 * (T + 2) + 2);
      else if (q == 3)   stage(4 * (T + 2) + 3);
      if (q == 0) asm volatile("s_waitcnt lgkmcnt(8)" ::: "memory");
      __builtin_amdgcn_s_barrier();
      asm volatile("s_waitcnt lgkmcnt(0)" ::: "memory");
      // --- MFMA cluster: one C-quadrant (2 m-frags x 4 n-frags) x K=64 ---
      __builtin_amdgcn_s_setprio(1);
      #pragma unroll
      for (int i = 0; i < 2; ++i)
        #pragma unroll
        for (int nj = 0; nj < 4; ++nj)
          #pragma unroll
          for (int kk = 0; kk < 2; ++kk)
            acc[q * 2 + i][nj] = __builtin_amdgcn_mfma_f32_16x16x32_bf16(
                aq[i][kk], bq[nj][kk], acc[q * 2 + i][nj], 0, 0, 0);
      __builtin_amdgcn_s_setprio(0);
      if (q == 3) {
        // drain B(T+1)+A(T+1); leave B(T+2) (4 loads) in flight.
        if (T >= NKT - 2) asm volatile("s_waitcnt vmcnt(0)" ::: "memory");
        else              asm volatile("s_waitcnt vmcnt(4)" ::: "memory");
      }
      __builtin_amdgcn_s_barrier();
    }
  }

  // epilogue: C = acc + bias ; C/D layout col=lane&15, row=(lane>>4)*4+reg
  #pragma unroll
  for (int nj = 0; nj < 4; ++nj) {
    const int col = bn * 256 + wn * 64 + nj * 16 + lr;
    const float bv = bias[col];
    #pragma unroll
    for (int mi = 0; mi < 8; ++mi) {
      const int row0 = bm * 256 + wm * 128 + mi * 16 + lg * 4;
      #pragma unroll
      for (int rr = 0; rr < 4; ++rr)
        C[(size_t)(row0 + rr) * OUT_ + col] = acc[mi][nj][rr] + bv;
    }
  }
}

extern "C" void kernel_launch(void* const* d_in, const int* in_sizes, int n_in,
                              void* d_out, int out_size, void* d_ws, size_t ws_size,
                              hipStream_t stream) {
  const float* x  = (const float*)d_in[0];   // [4,4096,2048]
  const float* Wb = (const float*)d_in[1];   // [2048,2048]
  const float* bb = (const float*)d_in[2];   // [2048]
  const float* rW = (const float*)d_in[3];   // [8,2048]
  const float* A  = (const float*)d_in[4];   // [8,16,2048]
  const float* Bw = (const float*)d_in[5];   // [8,2048,16]
  float* out = (float*)d_out;                // [4,4096,2048] fp32

  ushort_t* xext = (ushort_t*)d_ws;                                   // M_ x KX bf16
  ushort_t* wext = (ushort_t*)((char*)d_ws + (size_t)M_ * KX * 2);    // OUT_ x KX bf16
  int* eidx = (int*)((char*)d_ws + (size_t)M_ * KX * 2 + (size_t)OUT_ * KX * 2);
  ushort_t* aext = (ushort_t*)((char*)eidx + M_ * sizeof(int));       // 128 x D_ bf16

  wprep_all_kernel<<<OUT_ + (E_ * R_ * D_) / (256 * 8), 256, 0, stream>>>(Wb, Bw, A, wext, aext);
  router_kernel<<<M_ / 16, 256, 0, stream>>>(x, rW, eidx);
  hgemm_kernel<<<M_ / 32, 256, 0, stream>>>(x, aext, eidx, xext);
  gemm_kernel<<<(M_ / 256) * (OUT_ / 256), 512, 0, stream>>>(xext, wext, bb, out);
}